// Round 5
// baseline (9877.607 us; speedup 1.0000x reference)
//
#include <hip/hip_runtime.h>
#include <math.h>

#define SS 512
#define BB 64
#define EE 256
#define HH 512
#define NT 9
#define NWG 256
#define GBG 32   // workgroups per batch-group barrier

// ws layout (float32 elements):
//  hs   : SS*BB*HH at 0        (hs[t] = h_t)
//  em   : SS*BB*NT at EM_OFF
//  num  : 64 at NUM_OFF
//  norm : 64 at NORM_OFF
//  cnt  : SS*8*16 u32 at BAR_OFF          (64B-strided counters [t][bg])
//  flag : SS*8*16 u32 after cnt
#define HS_ELEMS ((size_t)SS * BB * HH)
#define EM_OFF   HS_ELEMS
#define NUM_OFF  (EM_OFF + (size_t)SS * BB * NT)
#define NORM_OFF (NUM_OFF + 64)
#define BAR_OFF  (NORM_OFF + 64)
#define BAR_U32S ((size_t)SS * 8 * 16)

__global__ __launch_bounds__(256) void init_barriers(float* __restrict__ ws) {
    unsigned* bar = (unsigned*)(ws + BAR_OFF);
    size_t idx = (size_t)blockIdx.x * 256 + threadIdx.x;
    if (idx < 2 * BAR_U32S) bar[idx] = 0u;
}

// Persistent LSTM: 256 WGs x 512 threads, one step per (per-bg) barrier round.
// WG (slice = wg&31, bg = wg>>5): units slice*16..+16, batches bg*8..+8.
// Wave w: gate-rows w*8..w*8+7. Lane L: k-chunk [8L, 8L+8).
// Whh AND Wih live in REGISTERS (64+32 VGPR/lane) -> zero per-step weight
// traffic on any memory pipe. Gate partials reduced across the 64 k-lanes
// with a 6-round exchange-halves butterfly (lane L ends with row w*8+(L>>3),
// batch L&7). Cross-WG h exchange via RELAXED agent atomics (LLC-coherent).
__global__ __launch_bounds__(512) void lstm_persistent(
    const float* __restrict__ Whh, const float* __restrict__ Wih,
    const float* __restrict__ bih, const float* __restrict__ bhh,
    const float* __restrict__ emb, const int* __restrict__ x,
    float* __restrict__ ws)
{
    const int wg    = blockIdx.x;
    const int slice = wg & 31;
    const int bg    = wg >> 5;
    const int tid   = threadIdx.x;
    const int w     = tid >> 6;
    const int L     = tid & 63;
    const int bbase = bg * 8;

    float* hs = ws;
    unsigned* cnt  = (unsigned*)(ws + BAR_OFF);
    unsigned* flag = cnt + BAR_U32S;

    __shared__ float h_l[8 * 512];     // [b_l][k]
    __shared__ float gsm[64 * 9];      // [row][b] padded stride 9
    __shared__ float cs_l[16 * 8];     // c-state [unit_local][b_l]

    // ---- weights into registers ----
    float whh[8][8];   // [r][j], k = 8L + j
    float wih[8][4];   // [r][j], k = 4L + j, prescaled by sqrt(E)=16
#pragma unroll
    for (int r = 0; r < 8; r++) {
        int l  = w * 8 + r;
        int gr = (l >> 4) * HH + slice * 16 + (l & 15);
        float4 a0 = *(const float4*)(Whh + (size_t)gr * HH + 8 * L);
        float4 a1 = *(const float4*)(Whh + (size_t)gr * HH + 8 * L + 4);
        whh[r][0] = a0.x; whh[r][1] = a0.y; whh[r][2] = a0.z; whh[r][3] = a0.w;
        whh[r][4] = a1.x; whh[r][5] = a1.y; whh[r][6] = a1.z; whh[r][7] = a1.w;
        float4 wi = *(const float4*)(Wih + (size_t)gr * EE + 4 * L);
        wih[r][0] = wi.x * 16.0f; wih[r][1] = wi.y * 16.0f;
        wih[r][2] = wi.z * 16.0f; wih[r][3] = wi.w * 16.0f;
    }

    // bias preload (activation threads only)
    float bs0 = 0.f, bs1 = 0.f, bs2 = 0.f, bs3 = 0.f;
    if (tid < 128) {
        const int u  = tid & 15;
        const int bb = tid >> 4;
        const int gu = slice * 16 + u;
        bs0 = bih[0 * HH + gu] + bhh[0 * HH + gu];
        bs1 = bih[1 * HH + gu] + bhh[1 * HH + gu];
        bs2 = bih[2 * HH + gu] + bhh[2 * HH + gu];
        bs3 = bih[3 * HH + gu] + bhh[3 * HH + gu];
        cs_l[u * 8 + bb] = 0.0f;
    }

    // h_{-1} = 0
#pragma unroll
    for (int j = 0; j < 8; j++) h_l[j * 512 + tid] = 0.0f;

    // ---- ih gates for t=0 into acc ----
    float acc[64];     // [r*8 + b]
#pragma unroll
    for (int b = 0; b < 8; b++) {
        int xv = x[0 * BB + bbase + b];
        float4 e4 = *(const float4*)(emb + (size_t)xv * EE + 4 * L);
#pragma unroll
        for (int r = 0; r < 8; r++)
            acc[r * 8 + b] = wih[r][0] * e4.x + wih[r][1] * e4.y +
                             wih[r][2] * e4.z + wih[r][3] * e4.w;
    }
    __syncthreads();

    for (int t = 0; t < SS; t++) {
        // ---- hh gates: acc[r][b] += whh[r][:] . h[b][8L..8L+8) ----
#pragma unroll
        for (int b = 0; b < 8; b++) {
            float4 h0 = *(const float4*)(h_l + b * 512 + 8 * L);
            float4 h1 = *(const float4*)(h_l + b * 512 + 8 * L + 4);
#pragma unroll
            for (int r = 0; r < 8; r++) {
                acc[r * 8 + b] += whh[r][0] * h0.x + whh[r][1] * h0.y +
                                  whh[r][2] * h0.z + whh[r][3] * h0.w +
                                  whh[r][4] * h1.x + whh[r][5] * h1.y +
                                  whh[r][6] * h1.z + whh[r][7] * h1.w;
            }
        }

        // ---- 6-round exchange-halves butterfly over the 64 k-lanes ----
        // After round d: lane keeps values whose bit d matches its lane bit.
        // End: lane L holds full sum for value v = L -> (row w*8+(L>>3), b=L&7).
#pragma unroll
        for (int d = 5; d >= 0; d--) {
            const int  m    = 1 << d;
            const int  half = 1 << d;
            const bool up   = (L & m) != 0;
#pragma unroll
            for (int i = 0; i < half; i++) {
                float send = up ? acc[i] : acc[i + half];
                float recv = __shfl_xor(send, m, 64);
                acc[i] = (up ? acc[i + half] : acc[i]) + recv;
            }
        }
        gsm[(w * 8 + (L >> 3)) * 9 + (L & 7)] = acc[0];
        __syncthreads();

        // ---- activations + state update + h_t store (relaxed agent) ----
        if (tid < 128) {
            const int u  = tid & 15;
            const int bb = tid >> 4;
            const int gu = slice * 16 + u;
            float gi = gsm[(0 * 16 + u) * 9 + bb] + bs0;
            float gf = gsm[(1 * 16 + u) * 9 + bb] + bs1;
            float gg = gsm[(2 * 16 + u) * 9 + bb] + bs2;
            float go = gsm[(3 * 16 + u) * 9 + bb] + bs3;
            float i_ = 1.0f / (1.0f + expf(-gi));
            float f_ = 1.0f / (1.0f + expf(-gf));
            float o_ = 1.0f / (1.0f + expf(-go));
            const int gb = bbase + bb;
            float cn = f_ * cs_l[u * 8 + bb] + i_ * tanhf(gg);
            float hn = o_ * tanhf(cn);
            cs_l[u * 8 + bb] = cn;
            __hip_atomic_store(&hs[(size_t)t * BB * HH + (size_t)gb * HH + gu],
                               hn, __ATOMIC_RELAXED, __HIP_MEMORY_SCOPE_AGENT);
        }
        __syncthreads();   // vmcnt(0) before s_barrier: h stores at LLC

        // ---- arrive at per-bg barrier t ----
        if (tid == 0) {
            unsigned old = __hip_atomic_fetch_add(&cnt[((size_t)t * 8 + bg) * 16], 1u,
                                                  __ATOMIC_RELAXED,
                                                  __HIP_MEMORY_SCOPE_AGENT);
            if (old == GBG - 1)
                __hip_atomic_store(&flag[((size_t)t * 8 + bg) * 16], 1u,
                                   __ATOMIC_RELAXED, __HIP_MEMORY_SCOPE_AGENT);
        }

        if (t + 1 < SS) {
            // ---- ih(t+1) into acc, overlapped with the wait window ----
#pragma unroll
            for (int b = 0; b < 8; b++) {
                int xv = x[(t + 1) * BB + bbase + b];
                float4 e4 = *(const float4*)(emb + (size_t)xv * EE + 4 * L);
#pragma unroll
                for (int r = 0; r < 8; r++)
                    acc[r * 8 + b] = wih[r][0] * e4.x + wih[r][1] * e4.y +
                                     wih[r][2] * e4.z + wih[r][3] * e4.w;
            }
            if (tid == 0) {
                while (__hip_atomic_load(&flag[((size_t)t * 8 + bg) * 16],
                                         __ATOMIC_RELAXED,
                                         __HIP_MEMORY_SCOPE_AGENT) == 0u) {}
            }
            __syncthreads();

            // ---- stage h_t into LDS (relaxed agent loads from LLC) ----
            const float* hsrc = hs + (size_t)t * BB * HH + (size_t)bbase * HH;
#pragma unroll
            for (int j = 0; j < 8; j++) {
                int idx = j * 512 + tid;
                h_l[idx] = __hip_atomic_load(&hsrc[idx], __ATOMIC_RELAXED,
                                             __HIP_MEMORY_SCOPE_AGENT);
            }
            __syncthreads();
        }
    }
}

// one wave per (t,b): logits = h @ W_out^T + b_out, then log_softmax
__global__ __launch_bounds__(256) void emis_kernel(
    const float* __restrict__ Wout, const float* __restrict__ bout,
    float* __restrict__ ws)
{
    int wid = blockIdx.x * 4 + (threadIdx.x >> 6);  // t*64 + b
    int L   = threadIdx.x & 63;
    const float* h = ws + (size_t)wid * HH;
    float hv[8];
#pragma unroll
    for (int i = 0; i < 8; i++) hv[i] = h[i * 64 + L];
    float acc[9];
#pragma unroll
    for (int tg = 0; tg < 9; tg++) acc[tg] = 0.0f;
    for (int i = 0; i < 8; i++) {
#pragma unroll
        for (int tg = 0; tg < 9; tg++)
            acc[tg] += Wout[tg * HH + i * 64 + L] * hv[i];
    }
#pragma unroll
    for (int tg = 0; tg < 9; tg++) {
        acc[tg] += __shfl_xor(acc[tg], 1, 64);
        acc[tg] += __shfl_xor(acc[tg], 2, 64);
        acc[tg] += __shfl_xor(acc[tg], 4, 64);
        acc[tg] += __shfl_xor(acc[tg], 8, 64);
        acc[tg] += __shfl_xor(acc[tg], 16, 64);
        acc[tg] += __shfl_xor(acc[tg], 32, 64);
    }
    float lg[9];
#pragma unroll
    for (int tg = 0; tg < 9; tg++) lg[tg] = acc[tg] + bout[tg];
    float m = lg[0];
#pragma unroll
    for (int tg = 1; tg < 9; tg++) m = fmaxf(m, lg[tg]);
    float ssum = 0.0f;
#pragma unroll
    for (int tg = 0; tg < 9; tg++) ssum += expf(lg[tg] - m);
    float lse = m + logf(ssum);
    float myo = lg[0] - lse;
#pragma unroll
    for (int tg = 1; tg < 9; tg++) if (L == tg) myo = lg[tg] - lse;
    if (L < 9) ws[EM_OFF + (size_t)wid * 9 + L] = myo;
}

// merged CRF: blocks 0..7 numerator, 8..15 forward(logZ), 16..23 viterbi
__global__ __launch_bounds__(512) void crf_all(
    const int* __restrict__ x, const int* __restrict__ bio,
    const float* __restrict__ start_t, const float* __restrict__ end_t,
    const float* __restrict__ trans, float* __restrict__ ws,
    float* __restrict__ out)
{
    const float* em = ws + EM_OFF;
    const int role  = blockIdx.x >> 3;
    const int local = blockIdx.x & 7;
    const int tid   = threadIdx.x;

    __shared__ float sc[9][8];
    __shared__ unsigned char hist[SS - 1][8][9];

    if (role == 0) {
        int b = local * 8 + (tid >> 6);
        int L = tid & 63;
        float sum = 0.0f;
        int cntm = 0;
#pragma unroll
        for (int j = 0; j < 8; j++) {
            int s = j * 64 + L;
            int tg = bio[s * BB + b];
            bool mk = (x[s * BB + b] != 0);
            cntm += mk ? 1 : 0;
            if (s == 0) {
                sum += start_t[tg] + em[(size_t)b * 9 + tg];
            } else if (mk) {
                int tp = bio[(s - 1) * BB + b];
                sum += em[((size_t)s * BB + b) * 9 + tg] + trans[tp * 9 + tg];
            }
        }
#pragma unroll
        for (int d = 1; d < 64; d <<= 1) {
            sum += __shfl_xor(sum, d, 64);
            cntm += __shfl_xor(cntm, d, 64);
        }
        if (L == 0) {
            int se = cntm - 1;
            sum += end_t[bio[se * BB + b]];
            ws[NUM_OFF + b] = sum;
        }
        return;
    }

    const int b_l = tid & 7;
    const int j   = tid >> 3;          // active j < 9
    const int b   = local * 8 + b_l;
    float tc[9];
    if (j < 9) {
#pragma unroll
        for (int i = 0; i < 9; i++) tc[i] = trans[i * 9 + j];
        sc[j][b_l] = start_t[j] + em[(size_t)b * 9 + j];
    }
    __syncthreads();

    if (role == 1) {
        for (int s = 1; s < SS; s++) {
            float nv = 0.0f;
            if (j < 9) {
                float sv[9];
                float m = -3.4e38f;
#pragma unroll
                for (int i = 0; i < 9; i++) {
                    sv[i] = sc[i][b_l] + tc[i];
                    m = fmaxf(m, sv[i]);
                }
                float ssum = 0.0f;
#pragma unroll
                for (int i = 0; i < 9; i++) ssum += expf(sv[i] - m);
                nv = m + logf(ssum) + em[((size_t)s * BB + b) * 9 + j];
            }
            bool mk = (x[s * BB + b] != 0);
            __syncthreads();
            if (j < 9 && mk) sc[j][b_l] = nv;
            __syncthreads();
        }
        if (j == 0) {
            float m = -3.4e38f;
#pragma unroll
            for (int i = 0; i < 9; i++) m = fmaxf(m, sc[i][b_l] + end_t[i]);
            float ssum = 0.0f;
#pragma unroll
            for (int i = 0; i < 9; i++) ssum += expf(sc[i][b_l] + end_t[i] - m);
            ws[NORM_OFF + b] = m + logf(ssum);
        }
    } else {
        for (int s = 1; s < SS; s++) {
            float nv = 0.0f;
            if (j < 9) {
                float best = sc[0][b_l] + tc[0];
                int bi = 0;
#pragma unroll
                for (int i = 1; i < 9; i++) {
                    float v = sc[i][b_l] + tc[i];
                    if (v > best) { best = v; bi = i; }  // first-max = jnp.argmax
                }
                hist[s - 1][b_l][j] = (unsigned char)bi;
                nv = best + em[((size_t)s * BB + b) * 9 + j];
            }
            __syncthreads();
            if (j < 9) sc[j][b_l] = nv;
            __syncthreads();
        }
        if (tid < 8) {
            int bl = tid;
            int gb = local * 8 + bl;
            float best = sc[0][bl] + end_t[0];
            int cur = 0;
#pragma unroll
            for (int i = 1; i < 9; i++) {
                float v = sc[i][bl] + end_t[i];
                if (v > best) { best = v; cur = i; }
            }
            out[1 + (size_t)(SS - 1) * BB + gb] = (float)cur;
            for (int s = SS - 2; s >= 0; s--) {
                cur = hist[s][bl][cur];
                out[1 + (size_t)s * BB + gb] = (float)cur;
            }
        }
    }
}

__global__ __launch_bounds__(64) void final_llh(const float* __restrict__ ws,
                                               float* __restrict__ out)
{
    int L = threadIdx.x;
    float v = ws[NUM_OFF + L] - ws[NORM_OFF + L];
    v += __shfl_xor(v, 1, 64);
    v += __shfl_xor(v, 2, 64);
    v += __shfl_xor(v, 4, 64);
    v += __shfl_xor(v, 8, 64);
    v += __shfl_xor(v, 16, 64);
    v += __shfl_xor(v, 32, 64);
    if (L == 0) out[0] = -v;
}

extern "C" void kernel_launch(void* const* d_in, const int* in_sizes, int n_in,
                              void* d_out, int out_size, void* d_ws, size_t ws_size,
                              hipStream_t stream) {
    const int*   x       = (const int*)d_in[0];
    const int*   bio     = (const int*)d_in[1];
    const float* emb     = (const float*)d_in[2];
    const float* W_ih    = (const float*)d_in[3];
    const float* W_hh    = (const float*)d_in[4];
    const float* b_ih    = (const float*)d_in[5];
    const float* b_hh    = (const float*)d_in[6];
    const float* W_out   = (const float*)d_in[7];
    const float* b_out   = (const float*)d_in[8];
    const float* start_t = (const float*)d_in[9];
    const float* end_t   = (const float*)d_in[10];
    const float* trans   = (const float*)d_in[11];
    float* out = (float*)d_out;
    float* ws  = (float*)d_ws;

    init_barriers<<<512, 256, 0, stream>>>(ws);
    lstm_persistent<<<NWG, 512, 0, stream>>>(W_hh, W_ih, b_ih, b_hh, emb, x, ws);
    emis_kernel<<<SS * BB / 4, 256, 0, stream>>>(W_out, b_out, ws);
    crf_all<<<24, 512, 0, stream>>>(x, bio, start_t, end_t, trans, ws, out);
    final_llh<<<1, 64, 0, stream>>>(ws, out);
}